// Round 3
// baseline (668.835 us; speedup 1.0000x reference)
//
#include <hip/hip_runtime.h>
#include <math.h>

// ResBlock via bf16 MFMA implicit-GEMM conv3x3.
// B=16, C=256, H=W=96. Padded channels-last intermediates [16][98][98][256] bf16.

#define Bn 16
#define Cn 256
#define Hn 96
#define Wn 96
#define PH 98
#define PW 98
#define HW (Hn*Wn)

typedef __bf16 bf16x8 __attribute__((ext_vector_type(8)));
typedef float  f32x4  __attribute__((ext_vector_type(4)));

__device__ __forceinline__ unsigned short f2bf(float f) {
    unsigned int u = __float_as_uint(f);
    unsigned int r = (u + 0x7fffu + ((u >> 16) & 1u)) >> 16;
    return (unsigned short)r;
}

__device__ __forceinline__ void lds_load16(void* lds, const void* g) {
    auto gp = (const __attribute__((address_space(1))) char*)(unsigned long long)(uintptr_t)g;
    auto lp = (__attribute__((address_space(3))) char*)(unsigned int)(uintptr_t)lds;
    __builtin_amdgcn_global_load_lds(gp, lp, 16, 0, 0);
}

// ---- zero the padded border (h in {0,97} or w in {0,97}) of a CL tensor ----
__global__ __launch_bounds__(256)
void zero_border_k(unsigned short* __restrict__ t) {
    int idx = blockIdx.x * 256 + threadIdx.x;      // 16*388*32 = 198656 threads
    int oct = idx & 31;
    int rest = idx >> 5;
    int pidx = rest % 388;
    int b = rest / 388;
    int h, w;
    if (pidx < 98)       { h = 0;  w = pidx; }
    else if (pidx < 196) { h = 97; w = pidx - 98; }
    else if (pidx < 292) { h = pidx - 196 + 1; w = 0; }
    else                 { h = pidx - 292 + 1; w = 97; }
    size_t e = ((size_t)(b * PH + h) * PW + w) * 256 + oct * 8;
    *(uint4*)(t + e) = make_uint4(0u, 0u, 0u, 0u);
}

// ---- pack weights fp32 [co][ci][3][3] -> bf16 [cc][k9][c'][ci32] ----
template<bool PERM>
__global__ __launch_bounds__(256)
void pack_w_k(const float* __restrict__ w, unsigned short* __restrict__ wp) {
    int idx = blockIdx.x * 256 + threadIdx.x;      // 589824
    int ci_l = idx & 31;
    int c    = (idx >> 5) & 255;
    int v    = idx >> 13;          // 0..71
    int k9   = v % 9;
    int cc   = v / 9;
    int co;
    if (PERM) {
        co = (c < 86) ? c * 3 : (c < 171) ? (c - 86) * 3 + 1 : (c - 171) * 3 + 2;
    } else {
        co = c;
    }
    float val = w[((size_t)co * 256 + cc * 32 + ci_l) * 9 + k9];
    wp[idx] = f2bf(val);
}

// ---- x fp32 NCHW -> padded channels-last bf16 (interior only) ----
__global__ __launch_bounds__(256)
void transform_x_k(const float* __restrict__ x, unsigned short* __restrict__ xp) {
    __shared__ float s[32 * 33];
    const int t = threadIdx.x;
    const int col0 = blockIdx.x * 32;
    const int row  = blockIdx.y;
    const int z = blockIdx.z;
    const int b = z >> 3;
    const int ci0 = (z & 7) * 32;

    #pragma unroll
    for (int i = 0; i < 4; ++i) {
        int ci = i * 8 + (t >> 5);
        int px = t & 31;
        s[ci * 33 + px] = x[((size_t)(b * Cn + ci0 + ci)) * HW + row * Wn + col0 + px];
    }
    __syncthreads();
    const int px = t >> 3;
    const int c4 = (t & 7) * 4;
    ushort4 o;
    o.x = f2bf(s[(c4 + 0) * 33 + px]);
    o.y = f2bf(s[(c4 + 1) * 33 + px]);
    o.z = f2bf(s[(c4 + 2) * 33 + px]);
    o.w = f2bf(s[(c4 + 3) * 33 + px]);
    size_t e = ((size_t)(b * PH + row + 1) * PW + (col0 + px + 1)) * 256 + ci0 + c4;
    *(ushort4*)(xp + e) = o;
}

// ---- MFMA conv3x3: 64 co x (16x32 px) per block, 4 waves, K chunks of 32 ci ----
// T14 schedule: input chunk cc+1 prefetched global->reg during compute of cc;
// after the barrier only ds_writes + weight global_load_lds sit exposed.
// MODE 0: in = x_pad, out = a_cl (activation, channels already in concat order)
// MODE 1: in = a_cl,  out = fp32 NCHW conv*0.1 + x
template<int MODE>
__global__ __launch_bounds__(256, 2)
void conv_k(const unsigned short* __restrict__ in_cl,
            const unsigned short* __restrict__ wp,
            const float* __restrict__ prelu_w,
            const float* __restrict__ xres,
            void* __restrict__ outp)
{
    __shared__ unsigned short s_x[612 * 32];     // [pixel(18x34)][ci32]  39168 B
    __shared__ unsigned short s_w[9 * 64 * 32];  // [k9][co64][ci32]      36864 B

    const int tid = threadIdx.x;
    // XCD-chunked swizzle: 1152 = 8*144; co-group fastest within a chunk.
    const int bid = blockIdx.x;
    const int wg = (bid & 7) * 144 + (bid >> 3);
    const int co_base = (wg & 3) * 64;
    const int t2 = wg >> 2;            // 0..287
    const int tile = t2 % 18;
    const int b = t2 / 18;
    const int R0 = (tile / 3) * 16;    // padded-row base of halo
    const int C0 = (tile % 3) * 32;

    const int lane = tid & 63;
    const int wv = tid >> 6;
    const int l15 = lane & 15;
    const int qq = lane >> 4;

    const unsigned short* img = in_cl + (size_t)b * PH * PW * 256;

    // ---- precomputed staging maps ----
    // input: 612 px * 4 sixteen-byte parts = 2448 slots; 10 issues/thread
    int g_off[10]; bool vld[10];
    #pragma unroll
    for (int i = 0; i < 10; ++i) {
        int slot = i * 256 + tid;
        vld[i] = slot < 2448;
        int s2 = vld[i] ? slot : 0;
        int p  = s2 >> 2;
        int pr = p / 34, pc = p - pr * 34;
        g_off[i] = ((R0 + pr) * PW + (C0 + pc)) * 256 + (s2 & 3) * 8;
    }
    // weights: 9*64*4 = 2304 slots; exactly 9 issues/thread
    int w_off[9];
    #pragma unroll
    for (int i = 0; i < 9; ++i) {
        int slot = i * 256 + tid;
        int k9 = slot >> 8;
        int co = (slot >> 2) & 63;
        w_off[i] = (k9 * 256 + co_base + co) * 32 + (slot & 3) * 8;
    }

    // ---- prologue: stage chunk 0 (input + weights) direct global->LDS ----
    #pragma unroll
    for (int i = 0; i < 10; ++i)
        if (vld[i]) lds_load16(&s_x[(size_t)(i * 256 + tid) * 8], img + g_off[i]);
    #pragma unroll
    for (int i = 0; i < 9; ++i)
        lds_load16(&s_w[(size_t)(i * 256 + tid) * 8], wp + w_off[i]);

    f32x4 acc[4][8];
    #pragma unroll
    for (int m = 0; m < 4; ++m)
        #pragma unroll
        for (int n = 0; n < 8; ++n) acc[m][n] = 0.f;

    __syncthreads();

    for (int cc = 0; cc < 8; ++cc) {
        // ---- issue next input chunk global->reg (hidden under compute) ----
        uint4 rin[10];
        if (cc < 7) {
            #pragma unroll
            for (int i = 0; i < 10; ++i)
                if (vld[i]) rin[i] = *(const uint4*)(img + g_off[i] + (cc + 1) * 32);
            asm volatile("" ::: "memory");           // don't sink the loads
            __builtin_amdgcn_sched_barrier(0);
        }

        // ---- compute chunk cc ----
        #pragma unroll
        for (int k9 = 0; k9 < 9; ++k9) {
            const int kh = k9 / 3, kw = k9 - 3 * kh;
            bf16x8 af[4];
            #pragma unroll
            for (int m = 0; m < 4; ++m)
                af[m] = *(const bf16x8*)&s_w[(k9 * 64 + m * 16 + l15) * 32 + qq * 8];
            __builtin_amdgcn_s_setprio(1);
            #pragma unroll
            for (int n = 0; n < 8; ++n) {
                const int P = (4 * wv + (n >> 1) + kh) * 34 + (n & 1) * 16 + l15 + kw;
                const bf16x8 bf = *(const bf16x8*)&s_x[P * 32 + qq * 8];
                #pragma unroll
                for (int m = 0; m < 4; ++m)
                    acc[m][n] = __builtin_amdgcn_mfma_f32_16x16x32_bf16(af[m], bf, acc[m][n], 0, 0, 0);
            }
            __builtin_amdgcn_s_setprio(0);
        }

        __syncthreads();   // all waves done reading s_x / s_w of chunk cc

        if (cc < 7) {
            // write prefetched input regs to LDS; stream next weights to LDS
            #pragma unroll
            for (int i = 0; i < 10; ++i)
                if (vld[i]) *(uint4*)&s_x[(size_t)(i * 256 + tid) * 8] = rin[i];
            #pragma unroll
            for (int i = 0; i < 9; ++i)
                lds_load16(&s_w[(size_t)(i * 256 + tid) * 8],
                           wp + (size_t)(cc + 1) * 73728 + w_off[i]);
        }
        __syncthreads();   // drains vmcnt + lgkmcnt for the staging
    }

    if constexpr (MODE == 0) {
        const float pw = prelu_w[0];
        unsigned short* aout = (unsigned short*)outp;
        #pragma unroll
        for (int m = 0; m < 4; ++m) {
            const int cb = co_base + m * 16 + qq * 4;
            #pragma unroll
            for (int n = 0; n < 8; ++n) {
                const int row_p = 4 * wv + (n >> 1);
                const int col_p = (n & 1) * 16 + l15;
                size_t pix = ((size_t)(b * PH + R0 + row_p + 1)) * PW + (C0 + col_p + 1);
                ushort4 o;
                float r[4];
                #pragma unroll
                for (int j = 0; j < 4; ++j) {
                    const int c = cb + j;
                    float s = acc[m][n][j];
                    if (c < 86)        r[j] = s >= 0.f ? s : pw * s;
                    else if (c < 171)  r[j] = fmaxf(s, 0.f);
                    else {
                        float e = __expf(2.f * s);
                        r[j] = 1.f - 2.f / (e + 1.f);
                    }
                }
                o.x = f2bf(r[0]); o.y = f2bf(r[1]); o.z = f2bf(r[2]); o.w = f2bf(r[3]);
                *(ushort4*)(aout + pix * 256 + cb) = o;
            }
        }
    } else {
        float* fout = (float*)outp;
        #pragma unroll
        for (int m = 0; m < 4; ++m) {
            const int cb = co_base + m * 16 + qq * 4;
            #pragma unroll
            for (int n = 0; n < 8; ++n) {
                const int row_p = 4 * wv + (n >> 1);
                const int col_p = (n & 1) * 16 + l15;
                size_t base = ((size_t)(b * Cn + cb)) * HW + (size_t)(R0 + row_p) * Wn + (C0 + col_p);
                #pragma unroll
                for (int j = 0; j < 4; ++j)
                    fout[base + (size_t)j * HW] = acc[m][n][j] * 0.1f + xres[base + (size_t)j * HW];
            }
        }
    }
}

extern "C" void kernel_launch(void* const* d_in, const int* in_sizes, int n_in,
                              void* d_out, int out_size, void* d_ws, size_t ws_size,
                              hipStream_t stream) {
    const float* x  = (const float*)d_in[0];
    const float* w2 = (const float*)d_in[1];
    const float* w3 = (const float*)d_in[2];
    const float* pw = (const float*)d_in[3];
    float* out = (float*)d_out;
    char* ws = (char*)d_ws;

    // ws layout: a_cl (78,675,968 B) | wp2 (1,179,648 B) | wp3 (1,179,648 B)  = 81 MB
    unsigned short* a_cl = (unsigned short*)ws;
    unsigned short* wp2  = (unsigned short*)(ws + 78675968);
    unsigned short* wp3  = (unsigned short*)(ws + 78675968 + 1179648);
    // x_pad aliases d_out (78.7 MB <= 151 MB); dead before conv<1> writes d_out.
    unsigned short* x_pad = (unsigned short*)d_out;

    zero_border_k<<<776, 256, 0, stream>>>(x_pad);
    zero_border_k<<<776, 256, 0, stream>>>(a_cl);
    pack_w_k<true ><<<2304, 256, 0, stream>>>(w2, wp2);
    pack_w_k<false><<<2304, 256, 0, stream>>>(w3, wp3);
    transform_x_k<<<dim3(3, 96, 128), 256, 0, stream>>>(x, x_pad);

    conv_k<0><<<1152, 256, 0, stream>>>(x_pad, wp2, pw, nullptr, (void*)a_cl);
    conv_k<1><<<1152, 256, 0, stream>>>(a_cl, wp3, nullptr, x, (void*)out);
}

// Round 4
// 615.366 us; speedup vs baseline: 1.0869x; 1.0869x over previous
//
#include <hip/hip_runtime.h>
#include <math.h>

// ResBlock via bf16 MFMA implicit-GEMM conv3x3, T3/T4 pipelined schedule.
// B=16, C=256, H=W=96. Padded channels-last bf16 intermediates [16][98][98][256].

#define Bn 16
#define Cn 256
#define Hn 96
#define Wn 96
#define PH 98
#define PW 98
#define HW (Hn*Wn)

typedef __bf16 bf16x8 __attribute__((ext_vector_type(8)));
typedef float  f32x4  __attribute__((ext_vector_type(4)));

__device__ __forceinline__ unsigned short f2bf(float f) {
    unsigned int u = __float_as_uint(f);
    unsigned int r = (u + 0x7fffu + ((u >> 16) & 1u)) >> 16;
    return (unsigned short)r;
}

__device__ __forceinline__ void lds_load16(void* lds, const void* g) {
    auto gp = (const __attribute__((address_space(1))) char*)(unsigned long long)(uintptr_t)g;
    auto lp = (__attribute__((address_space(3))) char*)(unsigned int)(uintptr_t)lds;
    __builtin_amdgcn_global_load_lds(gp, lp, 16, 0, 0);
}

#define SB() __builtin_amdgcn_sched_barrier(0)
#define MEMFENCE() asm volatile("" ::: "memory")

// ---- zero the padded border of a CL tensor ----
__global__ __launch_bounds__(256)
void zero_border_k(unsigned short* __restrict__ t) {
    int idx = blockIdx.x * 256 + threadIdx.x;      // 16*388*32 threads
    int oct = idx & 31;
    int rest = idx >> 5;
    int pidx = rest % 388;
    int b = rest / 388;
    int h, w;
    if (pidx < 98)       { h = 0;  w = pidx; }
    else if (pidx < 196) { h = 97; w = pidx - 98; }
    else if (pidx < 292) { h = pidx - 196 + 1; w = 0; }
    else                 { h = pidx - 292 + 1; w = 97; }
    size_t e = ((size_t)(b * PH + h) * PW + w) * 256 + oct * 8;
    *(uint4*)(t + e) = make_uint4(0u, 0u, 0u, 0u);
}

// ---- pack weights fp32 [co][ci][3][3] -> bf16 [cc][k9][c'][ci32] ----
template<bool PERM>
__global__ __launch_bounds__(256)
void pack_w_k(const float* __restrict__ w, unsigned short* __restrict__ wp) {
    int idx = blockIdx.x * 256 + threadIdx.x;      // 589824
    int ci_l = idx & 31;
    int c    = (idx >> 5) & 255;
    int v    = idx >> 13;          // 0..71
    int k9   = v % 9;
    int cc   = v / 9;
    int co;
    if (PERM) {
        co = (c < 86) ? c * 3 : (c < 171) ? (c - 86) * 3 + 1 : (c - 171) * 3 + 2;
    } else {
        co = c;
    }
    float val = w[((size_t)co * 256 + cc * 32 + ci_l) * 9 + k9];
    wp[idx] = f2bf(val);
}

// ---- x fp32 NCHW -> padded channels-last bf16 (interior only) ----
__global__ __launch_bounds__(256)
void transform_x_k(const float* __restrict__ x, unsigned short* __restrict__ xp) {
    __shared__ float s[32 * 33];
    const int t = threadIdx.x;
    const int col0 = blockIdx.x * 32;
    const int row  = blockIdx.y;
    const int z = blockIdx.z;
    const int b = z >> 3;
    const int ci0 = (z & 7) * 32;

    #pragma unroll
    for (int i = 0; i < 4; ++i) {
        int ci = i * 8 + (t >> 5);
        int px = t & 31;
        s[ci * 33 + px] = x[((size_t)(b * Cn + ci0 + ci)) * HW + row * Wn + col0 + px];
    }
    __syncthreads();
    const int px = t >> 3;
    const int c4 = (t & 7) * 4;
    ushort4 o;
    o.x = f2bf(s[(c4 + 0) * 33 + px]);
    o.y = f2bf(s[(c4 + 1) * 33 + px]);
    o.z = f2bf(s[(c4 + 2) * 33 + px]);
    o.w = f2bf(s[(c4 + 3) * 33 + px]);
    size_t e = ((size_t)(b * PH + row + 1) * PW + (col0 + px + 1)) * 256 + ci0 + c4;
    *(ushort4*)(xp + e) = o;
}

// ---- Pipelined MFMA conv3x3 ----
// 512 threads (8 waves), 1 block/CU. Block: 128 co x (12x32 px).
// wave wv: cg=wv&1 selects 64-co half, wrow=wv>>1 selects 3-row group.
// Per wave: m=4 co-frags x n=6 px-frags of 16x16, K chunks of 32 ci (8 chunks).
// Schedule: s_x double-buffered (gl_lds, counted vmcnt across raw barriers);
//           s_w single-buffered via global->reg->ds_write between barriers.
template<int MODE>
__global__ __launch_bounds__(512, 2)
void conv_k(const unsigned short* __restrict__ in_cl,
            const unsigned short* __restrict__ wp,
            const float* __restrict__ prelu_w,
            const float* __restrict__ xres,
            void* __restrict__ outp)
{
    __shared__ unsigned short s_x[2][2048 * 8];   // 2 x 32768 B  [px(14x34)][ci32]
    __shared__ unsigned short s_w[9 * 128 * 32];  // 73728 B      [k9][co128][ci32]

    const int tid = threadIdx.x;
    const int bid = blockIdx.x;
    // XCD-chunked bijective swizzle (768 = 8 * 96); co-half fastest.
    const int wg = (bid & 7) * 96 + (bid >> 3);
    const int blk_co = (wg & 1) * 128;
    const int t2 = wg >> 1;                // 0..383
    const int tile = t2 % 24;
    const int b = t2 / 24;
    const int R0 = (tile / 3) * 12;        // padded-coord halo base row
    const int C0 = (tile % 3) * 32;

    const int lane = tid & 63;
    const int wv = tid >> 6;
    const int l15 = lane & 15;
    const int qq = lane >> 4;
    const int cg = wv & 1;
    const int wrow = wv >> 1;

    const unsigned short* img = in_cl + (size_t)b * PH * PW * 256;

    // ---- staging maps ----
    // x: 476 px * 4 parts = 1904 slots, 4 issues/thread (clamped dups at end)
    int xg[4];
    #pragma unroll
    for (int i = 0; i < 4; ++i) {
        int slot = i * 512 + tid;
        if (slot > 1903) slot = 1903;
        int p = slot >> 2;
        int pr = p / 34, pc = p - pr * 34;
        xg[i] = ((R0 + pr) * PW + (C0 + pc)) * 256 + (slot & 3) * 8;
    }
    // w: 9*128*4 = 4608 slots, exactly 9/thread
    int wgo[9];
    #pragma unroll
    for (int i = 0; i < 9; ++i) {
        int slot = i * 512 + tid;
        int k9 = slot >> 9;
        int co = (slot >> 2) & 127;
        wgo[i] = (k9 * 256 + blk_co + co) * 32 + (slot & 3) * 8;
    }

    f32x4 acc[4][6];
    #pragma unroll
    for (int m = 0; m < 4; ++m)
        #pragma unroll
        for (int n = 0; n < 6; ++n) acc[m][n] = 0.f;

    // ---- prologue: x(0)->s_x[0], w(0)->s_w, x(1)->s_x[1] via gl_lds; w(1)->rw ----
    #pragma unroll
    for (int i = 0; i < 4; ++i) lds_load16(&s_x[0][(size_t)(i * 512 + tid) * 8], img + xg[i]);
    #pragma unroll
    for (int i = 0; i < 9; ++i) lds_load16(&s_w[(size_t)(i * 512 + tid) * 8], wp + wgo[i]);
    MEMFENCE(); SB();
    #pragma unroll
    for (int i = 0; i < 4; ++i) lds_load16(&s_x[1][(size_t)(i * 512 + tid) * 8], img + xg[i] + 32);
    MEMFENCE(); SB();
    uint4 rw[9];
    #pragma unroll
    for (int i = 0; i < 9; ++i) rw[i] = *(const uint4*)(wp + 73728 + wgo[i]);
    MEMFENCE(); SB();
    asm volatile("s_waitcnt vmcnt(13)" ::: "memory");   // x(0)+w(0) landed; x(1)+rw fly
    SB();
    __builtin_amdgcn_s_barrier();
    SB();

    for (int c = 0; c < 8; ++c) {
        const unsigned short* sxc = s_x[c & 1];
        #pragma unroll
        for (int k9 = 0; k9 < 9; ++k9) {
            const int kh = k9 / 3, kw = k9 - 3 * kh;
            bf16x8 af[4];
            #pragma unroll
            for (int m = 0; m < 4; ++m)
                af[m] = *(const bf16x8*)&s_w[(k9 * 128 + cg * 64 + m * 16 + l15) * 32 + qq * 8];
            __builtin_amdgcn_s_setprio(1);
            #pragma unroll
            for (int n = 0; n < 6; ++n) {
                const int P = (wrow * 3 + (n >> 1) + kh) * 34 + (n & 1) * 16 + l15 + kw;
                const bf16x8 bf = *(const bf16x8*)&sxc[P * 32 + qq * 8];
                #pragma unroll
                for (int m = 0; m < 4; ++m)
                    acc[m][n] = __builtin_amdgcn_mfma_f32_16x16x32_bf16(af[m], bf, acc[m][n], 0, 0, 0);
            }
            __builtin_amdgcn_s_setprio(0);
        }

        if (c < 7) {
            __builtin_amdgcn_s_barrier();               // all waves done reading s_w / s_x[c&1]
            SB();
            asm volatile("s_waitcnt vmcnt(0)" ::: "memory");  // rw(c+1) + x(c+1) landed (issued 1 phase ago)
            SB();
            #pragma unroll
            for (int i = 0; i < 9; ++i)
                *(uint4*)&s_w[(size_t)(i * 512 + tid) * 8] = rw[i];
            MEMFENCE(); SB();
            if (c < 6) {
                const int cc2 = c + 2;
                #pragma unroll
                for (int i = 0; i < 4; ++i)
                    lds_load16(&s_x[c & 1][(size_t)(i * 512 + tid) * 8], img + xg[i] + cc2 * 32);
                MEMFENCE(); SB();
                #pragma unroll
                for (int i = 0; i < 9; ++i)
                    rw[i] = *(const uint4*)(wp + (size_t)cc2 * 73728 + wgo[i]);
                MEMFENCE(); SB();
            }
            asm volatile("s_waitcnt lgkmcnt(0)" ::: "memory");  // ds_writes visible
            SB();
            __builtin_amdgcn_s_barrier();
            SB();
        }
    }

    // ---- epilogue (n-outer, m-inner for 64B-line write combining) ----
    if constexpr (MODE == 0) {
        const float pw = prelu_w[0];
        unsigned short* aout = (unsigned short*)outp;
        #pragma unroll
        for (int n = 0; n < 6; ++n) {
            const int row_p = wrow * 3 + (n >> 1);
            const int col_p = (n & 1) * 16 + l15;
            size_t pix = ((size_t)(b * PH + R0 + row_p + 1)) * PW + (C0 + col_p + 1);
            #pragma unroll
            for (int m = 0; m < 4; ++m) {
                const int cb = blk_co + cg * 64 + m * 16 + qq * 4;
                float r[4];
                #pragma unroll
                for (int j = 0; j < 4; ++j) {
                    const int ch = cb + j;
                    float s = acc[m][n][j];
                    if (ch < 86)        r[j] = s >= 0.f ? s : pw * s;
                    else if (ch < 171)  r[j] = fmaxf(s, 0.f);
                    else {
                        float e = __expf(2.f * s);
                        r[j] = 1.f - 2.f / (e + 1.f);
                    }
                }
                ushort4 o;
                o.x = f2bf(r[0]); o.y = f2bf(r[1]); o.z = f2bf(r[2]); o.w = f2bf(r[3]);
                *(ushort4*)(aout + pix * 256 + cb) = o;
            }
        }
    } else {
        float* fout = (float*)outp;
        #pragma unroll
        for (int n = 0; n < 6; ++n) {
            const int row_p = wrow * 3 + (n >> 1);
            const int col_p = (n & 1) * 16 + l15;
            #pragma unroll
            for (int m = 0; m < 4; ++m) {
                const int cb = blk_co + cg * 64 + m * 16 + qq * 4;
                size_t base = ((size_t)(b * Cn + cb)) * HW + (size_t)(R0 + row_p) * Wn + (C0 + col_p);
                #pragma unroll
                for (int j = 0; j < 4; ++j)
                    fout[base + (size_t)j * HW] = acc[m][n][j] * 0.1f + xres[base + (size_t)j * HW];
            }
        }
    }
}

extern "C" void kernel_launch(void* const* d_in, const int* in_sizes, int n_in,
                              void* d_out, int out_size, void* d_ws, size_t ws_size,
                              hipStream_t stream) {
    const float* x  = (const float*)d_in[0];
    const float* w2 = (const float*)d_in[1];
    const float* w3 = (const float*)d_in[2];
    const float* pw = (const float*)d_in[3];
    float* out = (float*)d_out;
    char* ws = (char*)d_ws;

    // ws layout: a_cl (78,675,968 B) | wp2 (1,179,648 B) | wp3 (1,179,648 B)  = 81 MB
    unsigned short* a_cl = (unsigned short*)ws;
    unsigned short* wp2  = (unsigned short*)(ws + 78675968);
    unsigned short* wp3  = (unsigned short*)(ws + 78675968 + 1179648);
    // x_pad aliases d_out (78.7 MB <= 151 MB); dead before conv<1> writes d_out.
    unsigned short* x_pad = (unsigned short*)d_out;

    zero_border_k<<<776, 256, 0, stream>>>(x_pad);
    zero_border_k<<<776, 256, 0, stream>>>(a_cl);
    pack_w_k<true ><<<2304, 256, 0, stream>>>(w2, wp2);
    pack_w_k<false><<<2304, 256, 0, stream>>>(w3, wp3);
    transform_x_k<<<dim3(3, 96, 128), 256, 0, stream>>>(x, x_pad);

    conv_k<0><<<768, 512, 0, stream>>>(x_pad, wp2, pw, nullptr, (void*)a_cl);
    conv_k<1><<<768, 512, 0, stream>>>(a_cl, wp3, nullptr, x, (void*)out);
}